// Round 2
// baseline (96.705 us; speedup 1.0000x reference)
//
#include <hip/hip_runtime.h>
#include <math.h>

// Geometry (fixed): 256 x 8192 x 3 f32 per input = 2,097,152 rows of 3.
#define N_ROWS   (256 * 8192)
#define BLOCK    256
#define ROWS_PER_THREAD 4
#define GRID     (N_ROWS / (BLOCK * ROWS_PER_THREAD))   // 2048; divides 2^32
#define F4_PER_BLOCK (BLOCK * 3)                        // 768 float4 per input

// XOR swizzle on float4 index: conflict-free for both the unit-stride writes
// and the stride-3 reads (3 coprime to 8 -> 8-lane alias sets cover all
// 8 bank-groups).
__device__ __forceinline__ int swz(int j) { return j ^ ((j >> 3) & 7); }

// Branchless acos, |err| < 6.8e-5 rad (Abramowitz-Stegun 4.4.45).
__device__ __forceinline__ float acos_fast(float x) {
    float ax = fabsf(x);
    float s  = sqrtf(fmaxf(0.0f, 1.0f - ax));
    float p  = fmaf(ax, -0.0187293f, 0.0742610f);
    p = fmaf(ax, p, -0.2121144f);
    p = fmaf(ax, p, 1.5707288f);
    float r = s * p;
    return (x >= 0.0f) ? r : (3.14159265358979f - r);
}

__global__ __launch_bounds__(BLOCK) void angle_fused(
    const float* __restrict__ o,
    const float* __restrict__ t,
    float* __restrict__ partial,
    unsigned int* __restrict__ cnt,
    float* __restrict__ out)
{
    __shared__ float4 so[F4_PER_BLOCK];
    __shared__ float4 st[F4_PER_BLOCK];

    const int tx  = threadIdx.x;
    const int bid = blockIdx.x;
    const long base4 = (long)bid * F4_PER_BLOCK;
    const float4* o4 = reinterpret_cast<const float4*>(o);
    const float4* t4 = reinterpret_cast<const float4*>(t);

    // Unit-stride coalesced global loads, swizzled LDS store.
#pragma unroll
    for (int k = 0; k < 3; ++k) {
        int j = k * BLOCK + tx;
        so[swz(j)] = o4[base4 + j];
        st[swz(j)] = t4[base4 + j];
    }
    __syncthreads();

    // Each thread: 12 contiguous floats = 4 rows of 3, via swizzled reads.
    float4 a0 = so[swz(3 * tx + 0)];
    float4 a1 = so[swz(3 * tx + 1)];
    float4 a2 = so[swz(3 * tx + 2)];
    float4 b0 = st[swz(3 * tx + 0)];
    float4 b1 = st[swz(3 * tx + 1)];
    float4 b2 = st[swz(3 * tx + 2)];

    float ox[4] = {a0.x, a0.w, a1.z, a2.y};
    float oy[4] = {a0.y, a1.x, a1.w, a2.z};
    float oz[4] = {a0.z, a1.y, a2.x, a2.w};
    float tx_[4] = {b0.x, b0.w, b1.z, b2.y};
    float ty_[4] = {b0.y, b1.x, b1.w, b2.z};
    float tz_[4] = {b0.z, b1.y, b2.x, b2.w};

    float s = 0.0f;
#pragma unroll
    for (int r = 0; r < 4; ++r) {
        float dot = ox[r] * tx_[r] + oy[r] * ty_[r] + oz[r] * tz_[r];
        float no2 = ox[r] * ox[r] + oy[r] * oy[r] + oz[r] * oz[r];
        float nt2 = tx_[r] * tx_[r] + ty_[r] * ty_[r] + tz_[r] * tz_[r];
        float c = dot * rsqrtf(no2) * rsqrtf(nt2);
        c = fminf(1.0f, fmaxf(-1.0f, c));
        s += acos_fast(c);
    }

    // Wave (64) reduce, then block reduce.
#pragma unroll
    for (int off = 32; off > 0; off >>= 1)
        s += __shfl_down(s, off, 64);

    __shared__ float waves[BLOCK / 64];
    __shared__ int isLast;
    const int lane = tx & 63;
    const int wid  = tx >> 6;
    if (lane == 0) waves[wid] = s;
    __syncthreads();

    if (tx == 0) {
        float bs = 0.0f;
#pragma unroll
        for (int w = 0; w < BLOCK / 64; ++w) bs += waves[w];
        __hip_atomic_store(&partial[bid], bs, __ATOMIC_RELAXED,
                           __HIP_MEMORY_SCOPE_AGENT);
        __threadfence();
        // Modulo ticket: correct for ANY initial counter value (incl. 0xAAAAAAAA
        // poison); 2048 divides 2^32 so wraparound keeps residues consistent.
        unsigned int ticket = __hip_atomic_fetch_add(cnt, 1u, __ATOMIC_ACQ_REL,
                                                     __HIP_MEMORY_SCOPE_AGENT);
        isLast = ((ticket % GRID) == (GRID - 1)) ? 1 : 0;
    }
    __syncthreads();

    if (isLast) {
        __threadfence();
        float fs = 0.0f;
        for (int i = tx; i < GRID; i += BLOCK)
            fs += __hip_atomic_load(&partial[i], __ATOMIC_RELAXED,
                                    __HIP_MEMORY_SCOPE_AGENT);
#pragma unroll
        for (int off = 32; off > 0; off >>= 1)
            fs += __shfl_down(fs, off, 64);
        if (lane == 0) waves[wid] = fs;
        __syncthreads();
        if (tx == 0) {
            float total = 0.0f;
#pragma unroll
            for (int w = 0; w < BLOCK / 64; ++w) total += waves[w];
            out[0] = total / (float)N_ROWS;
        }
    }
}

extern "C" void kernel_launch(void* const* d_in, const int* in_sizes, int n_in,
                              void* d_out, int out_size, void* d_ws, size_t ws_size,
                              hipStream_t stream)
{
    const float* outputs = (const float*)d_in[0];
    const float* targets = (const float*)d_in[1];
    float* out = (float*)d_out;
    float* partial = (float*)d_ws;                              // 8 KB
    unsigned int* cnt = (unsigned int*)((char*)d_ws + GRID * sizeof(float));

    angle_fused<<<GRID, BLOCK, 0, stream>>>(outputs, targets, partial, cnt, out);
}

// Round 3
// 16.619 us; speedup vs baseline: 5.8191x; 5.8191x over previous
//
#include <hip/hip_runtime.h>
#include <math.h>

// Geometry (fixed): 256 x 8192 x 3 f32 per input = 2,097,152 rows of 3.
#define N_ROWS   (256 * 8192)
#define BLOCK    256
#define ROWS_PER_THREAD 4
#define GRID     (N_ROWS / (BLOCK * ROWS_PER_THREAD))   // 2048
#define F4_PER_BLOCK (BLOCK * 3)                        // 768 float4 per input

// XOR swizzle on float4 index: conflict-free for both the unit-stride writes
// and the stride-3 reads (3 coprime to 8 -> alias sets cover all bank groups).
__device__ __forceinline__ int swz(int j) { return j ^ ((j >> 3) & 7); }

// Branchless acos, |err| < 6.8e-5 rad (Abramowitz-Stegun 4.4.45).
__device__ __forceinline__ float acos_fast(float x) {
    float ax = fabsf(x);
    float s  = sqrtf(fmaxf(0.0f, 1.0f - ax));
    float p  = fmaf(ax, -0.0187293f, 0.0742610f);
    p = fmaf(ax, p, -0.2121144f);
    p = fmaf(ax, p, 1.5707288f);
    float r = s * p;
    return (x >= 0.0f) ? r : (3.14159265358979f - r);
}

__global__ __launch_bounds__(BLOCK) void angle_partial(
    const float* __restrict__ o,
    const float* __restrict__ t,
    float* __restrict__ partial)
{
    __shared__ float4 so[F4_PER_BLOCK];
    __shared__ float4 st[F4_PER_BLOCK];

    const int tx  = threadIdx.x;
    const int bid = blockIdx.x;
    const long base4 = (long)bid * F4_PER_BLOCK;
    const float4* o4 = reinterpret_cast<const float4*>(o);
    const float4* t4 = reinterpret_cast<const float4*>(t);

    // Unit-stride coalesced global loads, swizzled LDS store.
#pragma unroll
    for (int k = 0; k < 3; ++k) {
        int j = k * BLOCK + tx;
        so[swz(j)] = o4[base4 + j];
        st[swz(j)] = t4[base4 + j];
    }
    __syncthreads();

    // Each thread: 12 contiguous floats = 4 rows of 3, via swizzled reads.
    float4 a0 = so[swz(3 * tx + 0)];
    float4 a1 = so[swz(3 * tx + 1)];
    float4 a2 = so[swz(3 * tx + 2)];
    float4 b0 = st[swz(3 * tx + 0)];
    float4 b1 = st[swz(3 * tx + 1)];
    float4 b2 = st[swz(3 * tx + 2)];

    float ox[4] = {a0.x, a0.w, a1.z, a2.y};
    float oy[4] = {a0.y, a1.x, a1.w, a2.z};
    float oz[4] = {a0.z, a1.y, a2.x, a2.w};
    float tx_[4] = {b0.x, b0.w, b1.z, b2.y};
    float ty_[4] = {b0.y, b1.x, b1.w, b2.z};
    float tz_[4] = {b0.z, b1.y, b2.x, b2.w};

    float s = 0.0f;
#pragma unroll
    for (int r = 0; r < 4; ++r) {
        float dot = ox[r] * tx_[r] + oy[r] * ty_[r] + oz[r] * tz_[r];
        float no2 = ox[r] * ox[r] + oy[r] * oy[r] + oz[r] * oz[r];
        float nt2 = tx_[r] * tx_[r] + ty_[r] * ty_[r] + tz_[r] * tz_[r];
        float c = dot * rsqrtf(no2) * rsqrtf(nt2);
        c = fminf(1.0f, fmaxf(-1.0f, c));
        s += acos_fast(c);
    }

    // Wave (64) reduce, then block reduce. No fences: the kernel boundary
    // is the synchronization (round 2's agent-scope fences cost 5.6x).
#pragma unroll
    for (int off = 32; off > 0; off >>= 1)
        s += __shfl_down(s, off, 64);

    __shared__ float waves[BLOCK / 64];
    const int lane = tx & 63;
    const int wid  = tx >> 6;
    if (lane == 0) waves[wid] = s;
    __syncthreads();

    if (tx == 0) {
        float bs = 0.0f;
#pragma unroll
        for (int w = 0; w < BLOCK / 64; ++w) bs += waves[w];
        partial[bid] = bs;
    }
}

__global__ __launch_bounds__(BLOCK) void angle_final(
    const float* __restrict__ partial,
    float* __restrict__ out)
{
    float s = 0.0f;
    for (int i = threadIdx.x; i < GRID; i += BLOCK)
        s += partial[i];

#pragma unroll
    for (int off = 32; off > 0; off >>= 1)
        s += __shfl_down(s, off, 64);

    __shared__ float waves[BLOCK / 64];
    const int lane = threadIdx.x & 63;
    const int wid  = threadIdx.x >> 6;
    if (lane == 0) waves[wid] = s;
    __syncthreads();

    if (threadIdx.x == 0) {
        float total = 0.0f;
#pragma unroll
        for (int w = 0; w < BLOCK / 64; ++w) total += waves[w];
        out[0] = total / (float)N_ROWS;
    }
}

extern "C" void kernel_launch(void* const* d_in, const int* in_sizes, int n_in,
                              void* d_out, int out_size, void* d_ws, size_t ws_size,
                              hipStream_t stream)
{
    const float* outputs = (const float*)d_in[0];
    const float* targets = (const float*)d_in[1];
    float* out = (float*)d_out;
    float* partial = (float*)d_ws;  // 8 KB scratch

    angle_partial<<<GRID, BLOCK, 0, stream>>>(outputs, targets, partial);
    angle_final<<<1, BLOCK, 0, stream>>>(partial, out);
}